// Round 2
// baseline (382.224 us; speedup 1.0000x reference)
//
#include <hip/hip_runtime.h>
#include <stdint.h>

#define NT 5
#define NC 32
#define NH 4
#define HW 4096             // 64*64
#define QS 0.51006972789f   // (1/sqrt(8)) * log2(e): fold scale + ln->log2 into q

// ---------------- Kernel A: per-pixel QKV projection ----------------
// q  -> fp32 [bt][head][pix][8], pre-scaled by QS (2 float4 / pixel-head)
// kv -> fp32 [bt][head][pix][k0..k7,v0..v7] (4 float4 / pixel-head)
__global__ __launch_bounds__(256) void qkv_kernel(
    const float* __restrict__ x,
    const float* __restrict__ Wq, const float* __restrict__ Wk,
    const float* __restrict__ Wv,
    float4* __restrict__ qbuf, float4* __restrict__ kvbuf)
{
  const int p   = blockIdx.x * 256 + threadIdx.x;   // 0..40959
  const int bt  = p >> 12;
  const int pix = p & 4095;

  const float* xp = x + (size_t)bt * (NC * HW) + pix;
  float xc[NC];
  #pragma unroll
  for (int c = 0; c < NC; ++c) xc[c] = xp[(size_t)c * HW];

  #pragma unroll 1
  for (int h = 0; h < NH; ++h) {
    float qv[8], kv8[8], vv8[8];
    #pragma unroll
    for (int j = 0; j < 8; ++j) {
      const int o = h * 8 + j;
      float aq = 0.f, ak = 0.f, av = 0.f;
      #pragma unroll
      for (int c = 0; c < NC; ++c) {
        const float xv = xc[c];
        aq = fmaf(xv, Wq[o * NC + c], aq);
        ak = fmaf(xv, Wk[o * NC + c], ak);
        av = fmaf(xv, Wv[o * NC + c], av);
      }
      qv[j] = aq * QS; kv8[j] = ak; vv8[j] = av;
    }
    const size_t base = ((size_t)bt * NH + h) * HW + pix;
    qbuf[base * 2]      = make_float4(qv[0], qv[1], qv[2], qv[3]);
    qbuf[base * 2 + 1]  = make_float4(qv[4], qv[5], qv[6], qv[7]);
    kvbuf[base * 4]     = make_float4(kv8[0], kv8[1], kv8[2], kv8[3]);
    kvbuf[base * 4 + 1] = make_float4(kv8[4], kv8[5], kv8[6], kv8[7]);
    kvbuf[base * 4 + 2] = make_float4(vv8[0], vv8[1], vv8[2], vv8[3]);
    kvbuf[base * 4 + 3] = make_float4(vv8[4], vv8[5], vv8[6], vv8[7]);
  }
}

// ---------------- Kernel B: neighborhood attention ----------------
static __device__ __forceinline__ void upd(float e, float& m, float& l,
                                           float (&acc)[8],
                                           const float4& v0, const float4& v1) {
  float p;
  if (e > m) {               // rare after warm-up (~O(log L) times per thread)
    const float al = exp2f(m - e);   // m=-inf first time -> al=0, zeroes state
    m = e;
    l *= al;
    #pragma unroll
    for (int i = 0; i < 8; ++i) acc[i] *= al;
    p = 1.0f;
  } else {
    p = exp2f(e - m);
  }
  l += p;
  acc[0] = fmaf(p, v0.x, acc[0]); acc[1] = fmaf(p, v0.y, acc[1]);
  acc[2] = fmaf(p, v0.z, acc[2]); acc[3] = fmaf(p, v0.w, acc[3]);
  acc[4] = fmaf(p, v1.x, acc[4]); acc[5] = fmaf(p, v1.y, acc[5]);
  acc[6] = fmaf(p, v1.z, acc[6]); acc[7] = fmaf(p, v1.w, acc[7]);
}

template <int R, int D>
static __device__ __forceinline__ void attn_body(
    int b, int t, int h, int tx0, int ty0,
    const float4* __restrict__ qbuf, const float4* __restrict__ kvbuf,
    float* __restrict__ obuf)
{
  constexpr int LS = 2 * R + 1;
  const int lane = threadIdx.x;      // 64 lanes = 64 query PAIRS (16x8 tile)
  const int py = lane >> 3;
  const int pp = lane & 7;
  const int y  = ty0 + py;
  // pair (x0, x0+D); for D==2 interleave so the 16-wide tile is covered
  const int x0 = (D == 1) ? (tx0 + 2 * pp) : (tx0 + (pp & 1) + 4 * (pp >> 1));
  const int xB = x0 + D;

  const float4* qp = qbuf + (size_t)((b * NT + t) * NH + h) * (HW * 2);
  const float4 qA0 = qp[(y * 64 + x0) * 2], qA1 = qp[(y * 64 + x0) * 2 + 1];
  const float4 qB0 = qp[(y * 64 + xB) * 2], qB1 = qp[(y * 64 + xB) * 2 + 1];

  float mA = -INFINITY, mB = -INFINITY, lA = 0.f, lB = 0.f;
  float aA[8], aB[8];
  #pragma unroll
  for (int i = 0; i < 8; ++i) { aA[i] = 0.f; aB[i] = 0.f; }

  #pragma unroll 1
  for (int s = 0; s < NT; ++s) {
    const float4* kvs = kvbuf + (size_t)((b * NT + s) * NH + h) * (HW * 4);
    #pragma unroll 1
    for (int dy = 0; dy < LS; ++dy) {
      const int ky = y + (dy - R) * D;
      if ((unsigned)ky >= 64u) continue;           // OOB row == -inf == skip
      const float4* row = kvs + (size_t)ky * 256;  // 64 px * 4 float4
      #pragma unroll
      for (int j = 0; j <= LS; ++j) {              // key-x sweep shared by pair
        const int kx = x0 + (j - R) * D;
        if ((unsigned)kx < 64u) {
          const float4 k0 = row[kx * 4],     k1 = row[kx * 4 + 1];
          const float4 v0 = row[kx * 4 + 2], v1 = row[kx * 4 + 3];
          if (j < LS) {                            // query A uses j = 0..LS-1
            const float dA = fmaf(qA1.w, k1.w, fmaf(qA1.z, k1.z, fmaf(qA1.y, k1.y,
                             fmaf(qA1.x, k1.x, fmaf(qA0.w, k0.w, fmaf(qA0.z, k0.z,
                             fmaf(qA0.y, k0.y, qA0.x * k0.x)))))));
            upd(dA, mA, lA, aA, v0, v1);
          }
          if (j > 0) {                             // query B uses j = 1..LS
            const float dB = fmaf(qB1.w, k1.w, fmaf(qB1.z, k1.z, fmaf(qB1.y, k1.y,
                             fmaf(qB1.x, k1.x, fmaf(qB0.w, k0.w, fmaf(qB0.z, k0.z,
                             fmaf(qB0.y, k0.y, qB0.x * k0.x)))))));
            upd(dB, mB, lB, aB, v0, v1);
          }
        }
      }
    }
  }

  const float iA = 1.0f / lA, iB = 1.0f / lB;
  float* ob = obuf + (size_t)(b * NT + t) * HW * 32;   // [pix][32] channel-last
  float4* oA = (float4*)(ob + (size_t)(y * 64 + x0) * 32 + h * 8);
  float4* oB = (float4*)(ob + (size_t)(y * 64 + xB) * 32 + h * 8);
  oA[0] = make_float4(aA[0] * iA, aA[1] * iA, aA[2] * iA, aA[3] * iA);
  oA[1] = make_float4(aA[4] * iA, aA[5] * iA, aA[6] * iA, aA[7] * iA);
  oB[0] = make_float4(aB[0] * iB, aB[1] * iB, aB[2] * iB, aB[3] * iB);
  oB[1] = make_float4(aB[4] * iB, aB[5] * iB, aB[6] * iB, aB[7] * iB);
}

__global__ __launch_bounds__(64) void attn_kernel(
    const float4* __restrict__ qbuf, const float4* __restrict__ kvbuf,
    float* __restrict__ obuf)
{
  const int bid  = blockIdx.x;       // 1280 = 10(bt) * 4(head) * 32(tile)
  const int tile = bid & 31;
  const int h    = (bid >> 5) & 3;
  const int bt   = bid >> 7;
  const int t = bt % NT, b = bt / NT;
  const int tx0 = (tile & 3) * 16;
  const int ty0 = (tile >> 2) * 8;
  if      (h == 0) attn_body<3, 1>(b, t, 0, tx0, ty0, qbuf, kvbuf, obuf);
  else if (h == 1) attn_body<3, 2>(b, t, 1, tx0, ty0, qbuf, kvbuf, obuf);
  else if (h == 2) attn_body<4, 1>(b, t, 2, tx0, ty0, qbuf, kvbuf, obuf);
  else             attn_body<4, 2>(b, t, 3, tx0, ty0, qbuf, kvbuf, obuf);
}

// ---------------- Kernel C: output projection + residual ----------------
__global__ __launch_bounds__(256) void proj_kernel(
    const float* __restrict__ obuf, const float* __restrict__ x,
    const float* __restrict__ Wo, float* __restrict__ out)
{
  const int p   = blockIdx.x * 256 + threadIdx.x;
  const int bt  = p >> 12;
  const int pix = p & 4095;

  const float4* op4 = (const float4*)(obuf + (size_t)p * 32);
  float oc[32];
  #pragma unroll
  for (int i = 0; i < 8; ++i) {
    const float4 t4 = op4[i];
    oc[4 * i] = t4.x; oc[4 * i + 1] = t4.y; oc[4 * i + 2] = t4.z; oc[4 * i + 3] = t4.w;
  }
  const float* xp = x + (size_t)bt * (NC * HW) + pix;
  float* yp = out + (size_t)bt * (NC * HW) + pix;
  #pragma unroll 1
  for (int o = 0; o < NC; ++o) {
    float acc = xp[(size_t)o * HW];              // residual
    #pragma unroll
    for (int c = 0; c < NC; ++c)
      acc = fmaf(oc[c], Wo[o * NC + c], acc);
    yp[(size_t)o * HW] = acc;
  }
}

extern "C" void kernel_launch(void* const* d_in, const int* in_sizes, int n_in,
                              void* d_out, int out_size, void* d_ws, size_t ws_size,
                              hipStream_t stream)
{
  const float* x  = (const float*)d_in[0];
  const float* Wq = (const float*)d_in[1];
  const float* Wk = (const float*)d_in[2];
  const float* Wv = (const float*)d_in[3];
  const float* Wo = (const float*)d_in[4];

  char* ws = (char*)d_ws;
  float4* qbuf  = (float4*)ws;                        //  5,242,880 B
  float4* kvbuf = (float4*)(ws + 5242880);            // 10,485,760 B
  float*  obuf  = (float*)(ws + 5242880 + 10485760);  //  5,242,880 B

  qkv_kernel<<<160, 256, 0, stream>>>(x, Wq, Wk, Wv, qbuf, kvbuf);
  attn_kernel<<<1280, 64, 0, stream>>>((const float4*)qbuf, (const float4*)kvbuf, obuf);
  proj_kernel<<<160, 256, 0, stream>>>(obuf, x, Wo, (float*)d_out);
}

// Round 3
// 201.319 us; speedup vs baseline: 1.8986x; 1.8986x over previous
//
#include <hip/hip_runtime.h>
#include <hip/hip_bf16.h>
#include <stdint.h>

#define NT 5
#define NC 32
#define NH 4
#define HW 4096             // 64*64
#define QS 0.51006972789f   // (1/sqrt(8)) * log2(e): fold scale + ln->log2 into q

static __device__ __forceinline__ float bf_lo(uint32_t w) { return __uint_as_float(w << 16); }
static __device__ __forceinline__ float bf_hi(uint32_t w) { return __uint_as_float(w & 0xffff0000u); }
static __device__ __forceinline__ uint32_t pack_bf2(float a, float b) {
  union { __hip_bfloat162 h; uint32_t u; } u;
  u.h.x = __float2bfloat16(a);
  u.h.y = __float2bfloat16(b);
  return u.u;
}

// ---------------- Kernel A: per-pixel QKV projection (one head per block.y) ----
// q -> fp32 [bt][h][pix][8] prescaled by QS; k,v -> bf16-packed uint4 [bt][h][pix]
__global__ __launch_bounds__(256) void qkv_kernel(
    const float* __restrict__ x,
    const float* __restrict__ Wq, const float* __restrict__ Wk,
    const float* __restrict__ Wv,
    float4* __restrict__ qbuf, uint4* __restrict__ kbuf, uint4* __restrict__ vbuf)
{
  const int p   = blockIdx.x * 256 + threadIdx.x;   // 0..40959
  const int h   = blockIdx.y;                       // 0..3
  const int bt  = p >> 12;
  const int pix = p & 4095;

  const float* xp = x + (size_t)bt * (NC * HW) + pix;
  float xc[NC];
  #pragma unroll
  for (int c = 0; c < NC; ++c) xc[c] = xp[(size_t)c * HW];

  float qv[8], kv8[8], vv8[8];
  #pragma unroll
  for (int j = 0; j < 8; ++j) {
    const int o = h * 8 + j;
    float aq = 0.f, ak = 0.f, av = 0.f;
    #pragma unroll
    for (int c = 0; c < NC; ++c) {
      const float xv = xc[c];
      aq = fmaf(xv, Wq[o * NC + c], aq);
      ak = fmaf(xv, Wk[o * NC + c], ak);
      av = fmaf(xv, Wv[o * NC + c], av);
    }
    qv[j] = aq * QS; kv8[j] = ak; vv8[j] = av;
  }
  const size_t base = ((size_t)bt * NH + h) * HW + pix;
  qbuf[base * 2]     = make_float4(qv[0], qv[1], qv[2], qv[3]);
  qbuf[base * 2 + 1] = make_float4(qv[4], qv[5], qv[6], qv[7]);
  uint4 kk, vv;
  kk.x = pack_bf2(kv8[0], kv8[1]); kk.y = pack_bf2(kv8[2], kv8[3]);
  kk.z = pack_bf2(kv8[4], kv8[5]); kk.w = pack_bf2(kv8[6], kv8[7]);
  vv.x = pack_bf2(vv8[0], vv8[1]); vv.y = pack_bf2(vv8[2], vv8[3]);
  vv.z = pack_bf2(vv8[4], vv8[5]); vv.w = pack_bf2(vv8[6], vv8[7]);
  kbuf[base] = kk;
  vbuf[base] = vv;
}

// ---------------- Kernel B: neighborhood attention, frame-split ----------------
// Block = 320 threads (5 waves); wave s handles frame s for the same 16x8 tile
// of query PAIRS; partial (l, acc[8]) merged via LDS; no running max (scores
// are O(+-10) in log2 units -> exp2 safe in fp32).
template <int R, int D>
static __device__ __forceinline__ void attn_body(
    int b, int t, int h, int tx0, int ty0,
    const float4* __restrict__ qbuf, const uint4* __restrict__ kbuf,
    const uint4* __restrict__ vbuf, float* __restrict__ obuf,
    float* __restrict__ red)
{
  constexpr int LS = 2 * R + 1;
  const int tid  = threadIdx.x;
  const int s    = tid >> 6;         // frame 0..4
  const int lane = tid & 63;
  const int py = lane >> 3;
  const int pp = lane & 7;
  const int y  = ty0 + py;
  // pair (x0, x0+D); for D==2 interleave so the 16-wide tile is covered
  const int x0 = (D == 1) ? (tx0 + 2 * pp) : (tx0 + (pp & 1) + 4 * (pp >> 1));
  const int xB = x0 + D;

  const float4* qp = qbuf + (size_t)((b * NT + t) * NH + h) * (HW * 2);
  const float4 qA0 = qp[(y * 64 + x0) * 2], qA1 = qp[(y * 64 + x0) * 2 + 1];
  const float4 qB0 = qp[(y * 64 + xB) * 2], qB1 = qp[(y * 64 + xB) * 2 + 1];

  float lA = 0.f, lB = 0.f;
  float aA[8], aB[8];
  #pragma unroll
  for (int i = 0; i < 8; ++i) { aA[i] = 0.f; aB[i] = 0.f; }

  const uint4* ks = kbuf + (size_t)((b * NT + s) * NH + h) * HW;
  const uint4* vs = vbuf + (size_t)((b * NT + s) * NH + h) * HW;

  #pragma unroll 1
  for (int dy = 0; dy < LS; ++dy) {
    const int  ky  = y + (dy - R) * D;
    const bool okY = (unsigned)ky < 64u;
    const uint4* krow = ks + (okY ? ky : 0) * 64;
    const uint4* vrow = vs + (okY ? ky : 0) * 64;
    #pragma unroll
    for (int j = 0; j <= LS; ++j) {               // key-x sweep shared by pair
      const int  kx  = x0 + (j - R) * D;
      const bool ok  = okY && ((unsigned)kx < 64u);
      const int  kxc = ok ? kx : 0;               // branchless: clamped load
      const uint4 kr = krow[kxc];
      const uint4 vr = vrow[kxc];
      const float k0 = bf_lo(kr.x), k1 = bf_hi(kr.x), k2 = bf_lo(kr.y), k3 = bf_hi(kr.y),
                  k4 = bf_lo(kr.z), k5 = bf_hi(kr.z), k6 = bf_lo(kr.w), k7 = bf_hi(kr.w);
      const float v0 = bf_lo(vr.x), v1 = bf_hi(vr.x), v2 = bf_lo(vr.y), v3 = bf_hi(vr.y),
                  v4 = bf_lo(vr.z), v5 = bf_hi(vr.z), v6 = bf_lo(vr.w), v7 = bf_hi(vr.w);
      if (j < LS) {                               // query A uses j = 0..LS-1
        const float e = fmaf(qA1.w, k7, fmaf(qA1.z, k6, fmaf(qA1.y, k5, fmaf(qA1.x, k4,
                        fmaf(qA0.w, k3, fmaf(qA0.z, k2, fmaf(qA0.y, k1, qA0.x * k0)))))));
        const float p = ok ? exp2f(e) : 0.f;
        lA += p;
        aA[0] = fmaf(p, v0, aA[0]); aA[1] = fmaf(p, v1, aA[1]);
        aA[2] = fmaf(p, v2, aA[2]); aA[3] = fmaf(p, v3, aA[3]);
        aA[4] = fmaf(p, v4, aA[4]); aA[5] = fmaf(p, v5, aA[5]);
        aA[6] = fmaf(p, v6, aA[6]); aA[7] = fmaf(p, v7, aA[7]);
      }
      if (j > 0) {                                // query B uses j = 1..LS
        const float e = fmaf(qB1.w, k7, fmaf(qB1.z, k6, fmaf(qB1.y, k5, fmaf(qB1.x, k4,
                        fmaf(qB0.w, k3, fmaf(qB0.z, k2, fmaf(qB0.y, k1, qB0.x * k0)))))));
        const float p = ok ? exp2f(e) : 0.f;
        lB += p;
        aB[0] = fmaf(p, v0, aB[0]); aB[1] = fmaf(p, v1, aB[1]);
        aB[2] = fmaf(p, v2, aB[2]); aB[3] = fmaf(p, v3, aB[3]);
        aB[4] = fmaf(p, v4, aB[4]); aB[5] = fmaf(p, v5, aB[5]);
        aB[6] = fmaf(p, v6, aB[6]); aB[7] = fmaf(p, v7, aB[7]);
      }
    }
  }

  // ---- merge the 5 frame-partials via LDS (plain sums; no max needed) ----
  if (s > 0) {
    float* d = red + ((size_t)(s - 1) * 64 + lane) * 20;
    d[0] = lA; d[1] = lB;
    #pragma unroll
    for (int i = 0; i < 8; ++i) { d[2 + i] = aA[i]; d[10 + i] = aB[i]; }
  }
  __syncthreads();
  if (s == 0) {
    #pragma unroll
    for (int w = 0; w < 4; ++w) {
      const float* src = red + ((size_t)w * 64 + lane) * 20;
      lA += src[0]; lB += src[1];
      #pragma unroll
      for (int i = 0; i < 8; ++i) { aA[i] += src[2 + i]; aB[i] += src[10 + i]; }
    }
    const float iA = 1.0f / lA, iB = 1.0f / lB;
    float* ob = obuf + (size_t)(b * NT + t) * HW * 32;   // [pix][32] channel-last
    float4* oA = (float4*)(ob + (size_t)(y * 64 + x0) * 32 + h * 8);
    float4* oB = (float4*)(ob + (size_t)(y * 64 + xB) * 32 + h * 8);
    oA[0] = make_float4(aA[0] * iA, aA[1] * iA, aA[2] * iA, aA[3] * iA);
    oA[1] = make_float4(aA[4] * iA, aA[5] * iA, aA[6] * iA, aA[7] * iA);
    oB[0] = make_float4(aB[0] * iB, aB[1] * iB, aB[2] * iB, aB[3] * iB);
    oB[1] = make_float4(aB[4] * iB, aB[5] * iB, aB[6] * iB, aB[7] * iB);
  }
}

__global__ __launch_bounds__(320) void attn_kernel(
    const float4* __restrict__ qbuf, const uint4* __restrict__ kbuf,
    const uint4* __restrict__ vbuf, float* __restrict__ obuf)
{
  __shared__ float red[4 * 64 * 20];   // 20,480 B
  const int bid  = blockIdx.x;         // 1280 = 10(bt) * 32(tile) * 4(head)
  const int h    = bid & 3;            // head in low bits -> R3/R4 mix per CU
  const int tile = (bid >> 2) & 31;
  const int bt   = bid >> 7;
  const int t = bt % NT, b = bt / NT;
  const int tx0 = (tile & 3) * 16;
  const int ty0 = (tile >> 2) * 8;
  if      (h == 0) attn_body<3, 1>(b, t, 0, tx0, ty0, qbuf, kbuf, vbuf, obuf, red);
  else if (h == 1) attn_body<3, 2>(b, t, 1, tx0, ty0, qbuf, kbuf, vbuf, obuf, red);
  else if (h == 2) attn_body<4, 1>(b, t, 2, tx0, ty0, qbuf, kbuf, vbuf, obuf, red);
  else             attn_body<4, 2>(b, t, 3, tx0, ty0, qbuf, kbuf, vbuf, obuf, red);
}

// ---------------- Kernel C: output projection + residual (8 ch per block.y) ----
__global__ __launch_bounds__(256) void proj_kernel(
    const float* __restrict__ obuf, const float* __restrict__ x,
    const float* __restrict__ Wo, float* __restrict__ out)
{
  const int p   = blockIdx.x * 256 + threadIdx.x;
  const int og  = blockIdx.y;          // out-channel group: 8 channels
  const int bt  = p >> 12;
  const int pix = p & 4095;

  const float4* op4 = (const float4*)(obuf + (size_t)p * 32);
  float oc[32];
  #pragma unroll
  for (int i = 0; i < 8; ++i) {
    const float4 t4 = op4[i];
    oc[4 * i] = t4.x; oc[4 * i + 1] = t4.y; oc[4 * i + 2] = t4.z; oc[4 * i + 3] = t4.w;
  }
  const float* xp = x + (size_t)bt * (NC * HW) + pix;
  float* yp = out + (size_t)bt * (NC * HW) + pix;
  #pragma unroll
  for (int oo = 0; oo < 8; ++oo) {
    const int o = og * 8 + oo;
    float acc = xp[(size_t)o * HW];              // residual
    #pragma unroll
    for (int c = 0; c < NC; ++c)
      acc = fmaf(oc[c], Wo[o * NC + c], acc);
    yp[(size_t)o * HW] = acc;
  }
}

extern "C" void kernel_launch(void* const* d_in, const int* in_sizes, int n_in,
                              void* d_out, int out_size, void* d_ws, size_t ws_size,
                              hipStream_t stream)
{
  const float* x  = (const float*)d_in[0];
  const float* Wq = (const float*)d_in[1];
  const float* Wk = (const float*)d_in[2];
  const float* Wv = (const float*)d_in[3];
  const float* Wo = (const float*)d_in[4];

  char* ws = (char*)d_ws;
  float4* qbuf = (float4*)ws;                           // 5,242,880 B
  uint4*  kbuf = (uint4*)(ws + 5242880);                // 2,621,440 B
  uint4*  vbuf = (uint4*)(ws + 5242880 + 2621440);      // 2,621,440 B
  float*  obuf = (float*)(ws + 5242880 + 2 * 2621440);  // 5,242,880 B

  qkv_kernel<<<dim3(160, 4), 256, 0, stream>>>(x, Wq, Wk, Wv, qbuf, kbuf, vbuf);
  attn_kernel<<<1280, 320, 0, stream>>>(qbuf, kbuf, vbuf, obuf);
  proj_kernel<<<dim3(160, 4), 256, 0, stream>>>(obuf, x, Wo, (float*)d_out);
}